// Round 4
// baseline (2242.940 us; speedup 1.0000x reference)
//
#include <hip/hip_runtime.h>

typedef __bf16 bf16;
typedef bf16 bf16x8 __attribute__((ext_vector_type(8)));
typedef float f32x4 __attribute__((ext_vector_type(4)));

#define NB 256     // batch
#define TS 64      // timesteps
#define DD 1024    // input dim
#define HH 1024    // hidden
#define KTOT 3072  // D + 2H (fused GEMM K)
#define NOUT 4096  // 4H
#define KTILES 96  // KTOT/32
#define KSPLIT 4   // K-split factor (4 x 768)
#define KT_PER 24  // ktiles per split (96/4)
#define GITERS 12  // BK=64 iters per split
#define PSTRIDE (NB * NOUT)  // elems between preact partials

// Weights are fragment-tiled (16n x 32k tiles of 512 bf16 = 1KB; element
// (l,j): n = base+(l&15), k = kbase+(l>>4)*8+j) -> LDS staging is the exact
// linear lane*16B placement global_load_lds performs. Activations (Aop) are
// plain row-major bf16 (256 x 3072): cell packs unit-stride; the GEMM's
// global SOURCE addresses are per-lane (m173), LDS dest stays linear.

// async 16B global->LDS (gfx950); dest must be wave-uniform base (HW adds
// lane*16), source is per-lane.
static __device__ __forceinline__ void gload_lds16(const void* g, void* l) {
  __builtin_amdgcn_global_load_lds(
      (const __attribute__((address_space(1))) void*)g,
      (__attribute__((address_space(3))) void*)l, 16, 0, 0);
}

// Convert [Wx; Wh; Wattn] (3072 x 4096 f32, stacked on K) into tiled bf16.
__global__ __launch_bounds__(256) void convert_w(const float* __restrict__ Wx,
                                                 const float* __restrict__ Wh,
                                                 const float* __restrict__ Wattn,
                                                 bf16* __restrict__ Wt) {
  const int gid = blockIdx.x * 256 + threadIdx.x;  // one 16B chunk per thread
  const int tile = gid >> 6;                       // 0..24575
  const int l = gid & 63;
  const int ntile = tile / KTILES;
  const int ktile = tile % KTILES;
  const int n = ntile * 16 + (l & 15);
  const int k0 = ktile * 32 + (l >> 4) * 8;
  bf16x8 ovec;
#pragma unroll
  for (int j = 0; j < 8; ++j) {
    const int k = k0 + j;
    float v;
    if (k < DD)            v = Wx[(size_t)k * NOUT + n];
    else if (k < DD + HH)  v = Wh[(size_t)(k - DD) * NOUT + n];
    else                   v = Wattn[(size_t)(k - DD - HH) * NOUT + n];
    ovec[j] = (bf16)v;
  }
  *(bf16x8*)(Wt + (size_t)tile * 512 + l * 8) = ovec;
}

// Post-barrier tail shared by init/cell: scores -> softmax -> attn -> pack.
// Block = one n, 1024 threads (16 waves). h_sh[1024] already written.
// Wave w owns position p=w; lane accumulates over h = lane+64i; 5 ds_swizzle
// XOR butterflies reduce within each 32-lane half; halves summed via LDS.
static __device__ __forceinline__ void attn_tail(
    int n, int u, const float* __restrict__ A, bf16* __restrict__ Aop,
    const float* __restrict__ h_sh, float* __restrict__ scA,
    float* __restrict__ scB) {
  const int lane = u & 63, w = u >> 6;
  const float* ap = A + (size_t)n * (HH * 16) + w;  // column p=w
  float s = 0.f;
#pragma unroll
  for (int i = 0; i < 16; ++i) {
    const int idx = lane + 64 * i;
    s = fmaf(h_sh[idx], ap[(size_t)idx * 16], s);
  }
  s += __int_as_float(__builtin_amdgcn_ds_swizzle(__float_as_int(s), 0x041F));
  s += __int_as_float(__builtin_amdgcn_ds_swizzle(__float_as_int(s), 0x081F));
  s += __int_as_float(__builtin_amdgcn_ds_swizzle(__float_as_int(s), 0x101F));
  s += __int_as_float(__builtin_amdgcn_ds_swizzle(__float_as_int(s), 0x201F));
  s += __int_as_float(__builtin_amdgcn_ds_swizzle(__float_as_int(s), 0x401F));
  if (lane == 0) scA[w] = s;
  else if (lane == 32) scB[w] = s;
  __syncthreads();
  // softmax over 16 positions, redundant per thread (static -> registers)
  float e[16];
  float m = -3.0e38f;
#pragma unroll
  for (int p = 0; p < 16; ++p) {
    e[p] = (scA[p] + scB[p]) * 0.03125f;  // 1/sqrt(1024)
    m = fmaxf(m, e[p]);
  }
  float sum = 0.f;
#pragma unroll
  for (int p = 0; p < 16; ++p) {
    e[p] = expf(e[p] - m);
    sum += e[p];
  }
  const float inv = 1.f / sum;
  const float* arow = A + (size_t)n * (HH * 16) + (size_t)u * 16;  // 64B contig
  float av = 0.f;
#pragma unroll
  for (int p = 0; p < 16; ++p) av = fmaf(arow[p], e[p], av);
  Aop[(size_t)n * KTOT + 2 * HH + u] = (bf16)(av * inv);
}

// h0 = mean(A, axis=(2,3)); c0 = h0; pack [x0 | h0 | attn0].
__global__ __launch_bounds__(1024) void init_kernel(const float* __restrict__ A,
                                                    const float* __restrict__ x,
                                                    float* __restrict__ c_ws,
                                                    bf16* __restrict__ Aop) {
  __shared__ float h_sh[HH];
  __shared__ float scA[16], scB[16];
  const int n = blockIdx.x, u = threadIdx.x;
  const float* arow = A + (size_t)n * (HH * 16) + (size_t)u * 16;
  float h0 = 0.f;
#pragma unroll
  for (int p = 0; p < 16; ++p) h0 += arow[p];
  h0 *= 0.0625f;
  c_ws[n * HH + u] = h0;
  h_sh[u] = h0;
  Aop[(size_t)n * KTOT + HH + u] = (bf16)h0;
  Aop[(size_t)n * KTOT + u] = (bf16)x[(size_t)n * TS * DD + u];
  __syncthreads();
  attn_tail(n, u, A, Aop, h_sh, scA, scB);
}

// LSTM gates (sum of K-split partials + bias) + output + next-step attn/pack.
__global__ __launch_bounds__(1024) void cell_kernel(const float* __restrict__ preact,
                                                    const float* __restrict__ bias,
                                                    float* __restrict__ c_ws,
                                                    const float* __restrict__ A,
                                                    const float* __restrict__ x,
                                                    bf16* __restrict__ Aop,
                                                    float* __restrict__ out,
                                                    const int t) {
  __shared__ float h_sh[HH];
  __shared__ float scA[16], scB[16];
  const int n = blockIdx.x, u = threadIdx.x;
  const float* pr = preact + (size_t)n * NOUT;
#define PSUM(g) (pr[g * HH + u] + pr[PSTRIDE + g * HH + u] + pr[2 * PSTRIDE + g * HH + u] + pr[3 * PSTRIDE + g * HH + u] + bias[g * HH + u])
  const float ai = PSUM(0);
  const float af = PSUM(1);
  const float ao = PSUM(2);
  const float ag = PSUM(3);
#undef PSUM
  const float cold = c_ws[n * HH + u];
  const float si = 1.f / (1.f + expf(-ai));
  const float sf = 1.f / (1.f + expf(-af));
  const float so = 1.f / (1.f + expf(-ao));
  const float cn = sf * cold + si * tanhf(ag);
  const float hn = so * tanhf(cn);
  c_ws[n * HH + u] = cn;
  out[((size_t)n * TS + t) * HH + u] = hn;
  if (t == TS - 1) return;  // uniform: no next step to pack
  h_sh[u] = hn;
  Aop[(size_t)n * KTOT + HH + u] = (bf16)hn;
  Aop[(size_t)n * KTOT + u] = (bf16)x[((size_t)n * TS + t + 1) * DD + u];
  __syncthreads();
  attn_tail(n, u, A, Aop, h_sh, scA, scB);
}

// preact_part[ks](256x4096) = Aop(:, ks*768:+768) @ W(slice), bf16 MFMA.
// 64x64 tile, 4 waves (2x2 of 32x32), BK=64, global_load_lds double buffer.
// KSPLIT=4 -> 1024 wgs -> 4 wg/CU -> 4 waves/SIMD.
__global__ __launch_bounds__(256) void gemm_kernel(const bf16* __restrict__ Aop,
                                                   const bf16* __restrict__ Wt,
                                                   float* __restrict__ preact) {
  __shared__ __align__(16) bf16 lds[2][16 * 512];  // 16 tiles x 1KB per buffer
  const int b = blockIdx.x;
  // XCD map: xcd = b&7; each XCD keeps the same 8 col-tiles across rt and ks
  // -> its 3.1 MB weight slice stays L2-resident across all 64 steps.
  const int xcd = b & 7, idx = b >> 3;          // idx in [0,128)
  const int rt = idx & 3;                       // row tile (64 rows)
  const int rest = idx >> 2;                    // [0,32)
  const int ct = xcd * 8 + (rest & 7);          // col tile (64 cols)
  const int ks = rest >> 3;                     // K-split index [0,4)
  const int tid = threadIdx.x;
  const int lane = tid & 63, wid = tid >> 6;
  const int wr = wid >> 1, wc = wid & 1;

  // staging: thread issues tile-slots s = wid + q*4; s<8: A, else B.
  const bf16* gsrc[4];
  int gstep[4], ldsbase[4];
#pragma unroll
  for (int q = 0; q < 4; ++q) {
    const int s = wid + q * 4;
    ldsbase[q] = s * 512;  // wave-uniform LDS dest; HW places lane at +lane*16B
    if (s < 8) {
      const int row = rt * 64 + (s >> 1) * 16 + (lane & 15);
      const int k0 = ks * 768 + (s & 1) * 32 + (lane >> 4) * 8;
      gsrc[q] = Aop + (size_t)row * KTOT + k0;
      gstep[q] = 64;  // BK per iter
    } else {
      const int nt = ct * 4 + ((s - 8) >> 1);
      gsrc[q] = Wt + ((size_t)nt * KTILES + ks * KT_PER + (s & 1)) * 512 + lane * 8;
      gstep[q] = 1024;  // 2 tiles per iter
    }
  }

  f32x4 acc[2][2];
#pragma unroll
  for (int i = 0; i < 2; ++i)
#pragma unroll
    for (int j = 0; j < 2; ++j) acc[i][j] = (f32x4){0.f, 0.f, 0.f, 0.f};

  const int aoff0 = ((wr * 2 + 0) * 2) * 512 + lane * 8;
  const int aoff1 = ((wr * 2 + 1) * 2) * 512 + lane * 8;
  const int boff0 = (8 + (wc * 2 + 0) * 2) * 512 + lane * 8;
  const int boff1 = (8 + (wc * 2 + 1) * 2) * 512 + lane * 8;

  // prologue: stage buf0
#pragma unroll
  for (int q = 0; q < 4; ++q) {
    gload_lds16(gsrc[q], &lds[0][ldsbase[q]]);
    gsrc[q] += gstep[q];
  }

  for (int t = 0; t < GITERS; ++t) {
    __syncthreads();  // drains vmcnt -> buf[t&1] staged; buf[~t&1] readers done
    if (t < GITERS - 1) {  // stage other buffer; full compute phase in flight
#pragma unroll
      for (int q = 0; q < 4; ++q) {
        gload_lds16(gsrc[q], &lds[(t + 1) & 1][ldsbase[q]]);
        gsrc[q] += gstep[q];
      }
    }
    const bf16* buf = lds[t & 1];
#pragma unroll
    for (int kk = 0; kk < 2; ++kk) {
      const bf16x8 a0 = *(const bf16x8*)(buf + aoff0 + kk * 512);
      const bf16x8 a1 = *(const bf16x8*)(buf + aoff1 + kk * 512);
      const bf16x8 b0 = *(const bf16x8*)(buf + boff0 + kk * 512);
      const bf16x8 b1 = *(const bf16x8*)(buf + boff1 + kk * 512);
      acc[0][0] = __builtin_amdgcn_mfma_f32_16x16x32_bf16(a0, b0, acc[0][0], 0, 0, 0);
      acc[0][1] = __builtin_amdgcn_mfma_f32_16x16x32_bf16(a0, b1, acc[0][1], 0, 0, 0);
      acc[1][0] = __builtin_amdgcn_mfma_f32_16x16x32_bf16(a1, b0, acc[1][0], 0, 0, 0);
      acc[1][1] = __builtin_amdgcn_mfma_f32_16x16x32_bf16(a1, b1, acc[1][1], 0, 0, 0);
    }
  }

  // epilogue: C/D layout col=lane&15, row=(lane>>4)*4+r  [m89-verified]
  float* pp = preact + (size_t)ks * PSTRIDE;
#pragma unroll
  for (int i = 0; i < 2; ++i) {
#pragma unroll
    for (int j = 0; j < 2; ++j) {
      const int row0 = rt * 64 + wr * 32 + i * 16 + (lane >> 4) * 4;
      const int col = ct * 64 + wc * 32 + j * 16 + (lane & 15);
#pragma unroll
      for (int r = 0; r < 4; ++r)
        pp[(size_t)(row0 + r) * NOUT + col] = acc[i][j][r];
    }
  }
}

// ---------------------------------------------------------------------------
// ws layout (bytes):
//   [0, 25165824)            Wt      bf16 tiled weights (3072x4096)
//   [25165824, 26738688)     Aop     bf16 ROW-MAJOR operand (256x3072)
//   [26738688, 43515904)     preact  f32 x4 K-split partials (256x4096 each)
//   [43515904, 44564480)     c       f32 (256x1024)
// total ~44.6 MB
// ---------------------------------------------------------------------------
extern "C" void kernel_launch(void* const* d_in, const int* in_sizes, int n_in,
                              void* d_out, int out_size, void* d_ws, size_t ws_size,
                              hipStream_t stream) {
  const float* x     = (const float*)d_in[0];
  const float* A     = (const float*)d_in[1];
  const float* Wx    = (const float*)d_in[2];
  const float* Wh    = (const float*)d_in[3];
  const float* Wattn = (const float*)d_in[4];
  const float* bias  = (const float*)d_in[5];
  float* out = (float*)d_out;
  char* ws = (char*)d_ws;
  bf16* Wt      = (bf16*)(ws + 0);
  bf16* Aop     = (bf16*)(ws + 25165824);
  float* preact = (float*)(ws + 26738688);
  float* c_ws   = (float*)(ws + 43515904);

  convert_w<<<6144, 256, 0, stream>>>(Wx, Wh, Wattn, Wt);
  init_kernel<<<NB, 1024, 0, stream>>>(A, x, c_ws, Aop);
  for (int t = 0; t < TS; ++t) {
    gemm_kernel<<<NB * KSPLIT, 256, 0, stream>>>(Aop, Wt, preact);
    cell_kernel<<<NB, 1024, 0, stream>>>(preact, bias, c_ws, A, x, Aop, out, t);
  }
}